// Round 1
// baseline (679.407 us; speedup 1.0000x reference)
//
#include <hip/hip_runtime.h>

#define BB 2
#define VV 16000
#define PP 32
#define NVOX (BB*VV)      // 32000
#define NPTS (NVOX*PP)    // 1024000

// ---------------- zero the stats accumulators in ws ----------------
__global__ void kz(double* __restrict__ s) {
    if (threadIdx.x < 224) s[threadIdx.x] = 0.0;
}

// ---------------- k1: stats of h1pre (16 ch) over all points ----------------
__global__ __launch_bounds__(256) void k1(const float* __restrict__ vox,
                                          const int* __restrict__ coords,
                                          const float* __restrict__ W1,
                                          double* __restrict__ s1) {
    float sum[16], sq[16];
#pragma unroll
    for (int o = 0; o < 16; o++) { sum[o] = 0.f; sq[o] = 0.f; }
    const int stride = gridDim.x * blockDim.x;
    for (int i = blockIdx.x * blockDim.x + threadIdx.x; i < NPTS; i += stride) {
        const int vx = i >> 5;
        const float4 q = reinterpret_cast<const float4*>(vox)[i];
        const int4 c4 = reinterpret_cast<const int4*>(coords)[vx];
        const float cx = ((float)c4.w + 0.5f) * 0.16f + 0.0f;
        const float cy = ((float)c4.z + 0.5f) * 0.16f - 39.68f;
        const float cz = ((float)c4.y + 0.5f) * 4.0f  - 3.0f;
        const float f[8] = {q.x, q.y, q.z, q.x - cx, q.y - cy, q.z - cz, q.w, q.z};
#pragma unroll
        for (int o = 0; o < 16; o++) {
            float h = 0.f;
#pragma unroll
            for (int c = 0; c < 8; c++) h = fmaf(f[c], W1[o * 8 + c], h);
            sum[o] += h;
            sq[o] = fmaf(h, h, sq[o]);
        }
    }
    __shared__ double red[4][32];
    const int lane = threadIdx.x & 63, wv = threadIdx.x >> 6;
#pragma unroll
    for (int o = 0; o < 16; o++) {
        float s = sum[o], g = sq[o];
#pragma unroll
        for (int m = 1; m < 64; m <<= 1) { s += __shfl_xor(s, m); g += __shfl_xor(g, m); }
        if (lane == 0) { red[wv][o] = (double)s; red[wv][16 + o] = (double)g; }
    }
    __syncthreads();
    if (threadIdx.x < 32) {
        double t = red[0][threadIdx.x] + red[1][threadIdx.x] + red[2][threadIdx.x] + red[3][threadIdx.x];
        atomicAdd(&s1[threadIdx.x], t);
    }
}

// ---------------- k2: stats of h2pre (32 ch) over all points ----------------
__global__ __launch_bounds__(256) void k2(const float* __restrict__ vox,
                                          const int* __restrict__ coords,
                                          const int* __restrict__ nump,
                                          const float* __restrict__ W1,
                                          const float* __restrict__ g1v,
                                          const float* __restrict__ b1v,
                                          const float* __restrict__ W2,
                                          const double* __restrict__ s1,
                                          double* __restrict__ s2) {
    __shared__ float a1s[16], c1s[16];
    if (threadIdx.x < 16) {
        const int o = threadIdx.x;
        const double mean = s1[o] * (1.0 / NPTS);
        const double var  = s1[16 + o] * (1.0 / NPTS) - mean * mean;
        const float inv = rsqrtf((float)var + 1e-3f);
        const float a = g1v[o] * inv;
        a1s[o] = a;
        c1s[o] = b1v[o] - (float)mean * a;
    }
    __syncthreads();

    float sum[32], sq[32];
#pragma unroll
    for (int o = 0; o < 32; o++) { sum[o] = 0.f; sq[o] = 0.f; }

    const int p = threadIdx.x & 31;
    const int gid = (blockIdx.x * blockDim.x + threadIdx.x) >> 5;
    const int ngr = (gridDim.x * blockDim.x) >> 5;
    for (int vx = gid; vx < NVOX; vx += ngr) {
        const int4 c4 = reinterpret_cast<const int4*>(coords)[vx];
        const int np = nump[vx];
        const float4 q = reinterpret_cast<const float4*>(vox)[(vx << 5) + p];
        const float cx = ((float)c4.w + 0.5f) * 0.16f + 0.0f;
        const float cy = ((float)c4.z + 0.5f) * 0.16f - 39.68f;
        const float cz = ((float)c4.y + 0.5f) * 4.0f  - 3.0f;
        const float f[8] = {q.x, q.y, q.z, q.x - cx, q.y - cy, q.z - cz, q.w, q.z};
        float cb[32];
#pragma unroll
        for (int o = 0; o < 16; o++) {
            float h = 0.f;
#pragma unroll
            for (int c = 0; c < 8; c++) h = fmaf(f[c], W1[o * 8 + c], h);
            cb[o] = fmaxf(fmaf(a1s[o], h, c1s[o]), 0.f);   // h1 (post BN+relu)
        }
        // mx over the 32 points (unmasked), per channel
#pragma unroll
        for (int o = 0; o < 16; o++) {
            float t = cb[o];
#pragma unroll
            for (int m = 1; m < 32; m <<= 1) t = fmaxf(t, __shfl_xor(t, m));
            cb[16 + o] = t;
        }
        const float mk = (p < np) ? 1.f : 0.f;
#pragma unroll
        for (int o = 0; o < 32; o++) cb[o] *= mk;
        // h2pre = cb @ W2^T, accumulate stats
#pragma unroll
        for (int o = 0; o < 32; o++) {
            float h = 0.f;
#pragma unroll
            for (int c = 0; c < 32; c++) h = fmaf(cb[c], W2[o * 32 + c], h);
            sum[o] += h;
            sq[o] = fmaf(h, h, sq[o]);
        }
    }

    __shared__ double red[4][64];
    const int lane = threadIdx.x & 63, wv = threadIdx.x >> 6;
#pragma unroll
    for (int o = 0; o < 32; o++) {
        float s = sum[o], g = sq[o];
#pragma unroll
        for (int m = 1; m < 64; m <<= 1) { s += __shfl_xor(s, m); g += __shfl_xor(g, m); }
        if (lane == 0) { red[wv][o] = (double)s; red[wv][32 + o] = (double)g; }
    }
    __syncthreads();
    if (threadIdx.x < 64) {
        double t = red[0][threadIdx.x] + red[1][threadIdx.x] + red[2][threadIdx.x] + red[3][threadIdx.x];
        atomicAdd(&s2[threadIdx.x], t);
    }
}

// ---------------- k3: recompute, voxel features, final matmul, statsf ----------------
__global__ __launch_bounds__(256) void k3(const float* __restrict__ vox,
                                          const int* __restrict__ coords,
                                          const int* __restrict__ nump,
                                          const float* __restrict__ W1,
                                          const float* __restrict__ g1v,
                                          const float* __restrict__ b1v,
                                          const float* __restrict__ W2,
                                          const float* __restrict__ g2v,
                                          const float* __restrict__ b2v,
                                          const float* __restrict__ Wf,
                                          const double* __restrict__ s1,
                                          const double* __restrict__ s2,
                                          double* __restrict__ sf,
                                          float* __restrict__ outp) {
    __shared__ __align__(16) float wf[64 * 68];
    __shared__ float a1s[16], c1s[16], a2s[32], c2s[32];
    for (int i = threadIdx.x; i < 64 * 64; i += 256) {
        const int r = i >> 6, c = i & 63;
        wf[r * 68 + c] = Wf[i];
    }
    if (threadIdx.x < 16) {
        const int o = threadIdx.x;
        const double mean = s1[o] * (1.0 / NPTS);
        const double var  = s1[16 + o] * (1.0 / NPTS) - mean * mean;
        const float inv = rsqrtf((float)var + 1e-3f);
        const float a = g1v[o] * inv;
        a1s[o] = a;
        c1s[o] = b1v[o] - (float)mean * a;
    }
    if (threadIdx.x >= 32 && threadIdx.x < 64) {
        const int o = threadIdx.x - 32;
        const double mean = s2[o] * (1.0 / NPTS);
        const double var  = s2[32 + o] * (1.0 / NPTS) - mean * mean;
        const float inv = rsqrtf((float)var + 1e-3f);
        const float a = g2v[o] * inv;
        a2s[o] = a;
        c2s[o] = b2v[o] - (float)mean * a;
    }
    __syncthreads();

    float ts0 = 0.f, tq0 = 0.f, ts1 = 0.f, tq1 = 0.f;
    const int p = threadIdx.x & 31;
    const int gid = (blockIdx.x * blockDim.x + threadIdx.x) >> 5;
    const int ngr = (gridDim.x * blockDim.x) >> 5;
    for (int vx = gid; vx < NVOX; vx += ngr) {
        const int4 c4 = reinterpret_cast<const int4*>(coords)[vx];
        const int np = nump[vx];
        const float4 q = reinterpret_cast<const float4*>(vox)[(vx << 5) + p];
        const float cx = ((float)c4.w + 0.5f) * 0.16f + 0.0f;
        const float cy = ((float)c4.z + 0.5f) * 0.16f - 39.68f;
        const float cz = ((float)c4.y + 0.5f) * 4.0f  - 3.0f;
        const float f[8] = {q.x, q.y, q.z, q.x - cx, q.y - cy, q.z - cz, q.w, q.z};
        float cb[32];
#pragma unroll
        for (int o = 0; o < 16; o++) {
            float h = 0.f;
#pragma unroll
            for (int c = 0; c < 8; c++) h = fmaf(f[c], W1[o * 8 + c], h);
            cb[o] = fmaxf(fmaf(a1s[o], h, c1s[o]), 0.f);
        }
#pragma unroll
        for (int o = 0; o < 16; o++) {
            float t = cb[o];
#pragma unroll
            for (int m = 1; m < 32; m <<= 1) t = fmaxf(t, __shfl_xor(t, m));
            cb[16 + o] = t;
        }
        const float mk = (p < np) ? 1.f : 0.f;
#pragma unroll
        for (int o = 0; o < 32; o++) cb[o] *= mk;

        float vf0[32], vf1[32];
#pragma unroll
        for (int o = 0; o < 32; o++) {
            float h = 0.f;
#pragma unroll
            for (int c = 0; c < 32; c++) h = fmaf(cb[c], W2[o * 32 + c], h);
            const float h2 = fmaxf(fmaf(a2s[o], h, c2s[o]), 0.f);
            float tm = mk * h2;   // masked value
            float ta = h2;        // unmasked
#pragma unroll
            for (int m = 1; m < 32; m <<= 1) {
                tm = fmaxf(tm, __shfl_xor(tm, m));
                ta = fmaxf(ta, __shfl_xor(ta, m));
            }
            vf0[o] = tm;
            vf1[o] = ta;
        }
        const float gate = (np > 0) ? 1.f : 0.f;

        float o0a = 0.f, o0b = 0.f, o1a = 0.f, o1b = 0.f;
#pragma unroll
        for (int c = 0; c < 32; c += 4) {
            const float4 wA = *reinterpret_cast<const float4*>(&wf[p * 68 + c]);
            const float4 wB = *reinterpret_cast<const float4*>(&wf[p * 68 + 32 + c]);
            const float4 wC = *reinterpret_cast<const float4*>(&wf[(p + 32) * 68 + c]);
            const float4 wD = *reinterpret_cast<const float4*>(&wf[(p + 32) * 68 + 32 + c]);
            o0a += wA.x * vf0[c] + wA.y * vf0[c + 1] + wA.z * vf0[c + 2] + wA.w * vf0[c + 3];
            o0b += wB.x * vf1[c] + wB.y * vf1[c + 1] + wB.z * vf1[c + 2] + wB.w * vf1[c + 3];
            o1a += wC.x * vf0[c] + wC.y * vf0[c + 1] + wC.z * vf0[c + 2] + wC.w * vf0[c + 3];
            o1b += wD.x * vf1[c] + wD.y * vf1[c + 1] + wD.z * vf1[c + 2] + wD.w * vf1[c + 3];
        }
        const float r0 = o0a + gate * o0b;
        const float r1 = o1a + gate * o1b;
        outp[(vx << 6) + p] = r0;
        outp[(vx << 6) + 32 + p] = r1;
        ts0 += r0; tq0 = fmaf(r0, r0, tq0);
        ts1 += r1; tq1 = fmaf(r1, r1, tq1);
    }

    // statsf reduce: lane p of each half-wave owns channels p and p+32
    ts0 += __shfl_xor(ts0, 32); tq0 += __shfl_xor(tq0, 32);
    ts1 += __shfl_xor(ts1, 32); tq1 += __shfl_xor(tq1, 32);
    __shared__ double red[4][32][4];
    const int wv = threadIdx.x >> 6, ln = threadIdx.x & 63;
    if (ln < 32) {
        red[wv][ln][0] = (double)ts0; red[wv][ln][1] = (double)tq0;
        red[wv][ln][2] = (double)ts1; red[wv][ln][3] = (double)tq1;
    }
    __syncthreads();
    if (threadIdx.x < 32) {
        const int pp = threadIdx.x;
        double S0 = 0, Q0 = 0, S1 = 0, Q1 = 0;
#pragma unroll
        for (int w = 0; w < 4; w++) {
            S0 += red[w][pp][0]; Q0 += red[w][pp][1];
            S1 += red[w][pp][2]; Q1 += red[w][pp][3];
        }
        atomicAdd(&sf[pp], S0);       atomicAdd(&sf[64 + pp], Q0);
        atomicAdd(&sf[32 + pp], S1);  atomicAdd(&sf[96 + pp], Q1);
    }
}

// ---------------- k4: final BN, in-place on d_out ----------------
__global__ __launch_bounds__(256) void k4(float* __restrict__ outp,
                                          const float* __restrict__ gf,
                                          const float* __restrict__ bf,
                                          const double* __restrict__ sf) {
    const int tid = blockIdx.x * blockDim.x + threadIdx.x;
    const int o = tid & 63;
    const double mean = sf[o] * (1.0 / NVOX);
    const double var  = sf[64 + o] * (1.0 / NVOX) - mean * mean;
    const float a = gf[o] * rsqrtf((float)var + 1e-5f);
    const float c = bf[o] - (float)mean * a;
    const int stride = gridDim.x * blockDim.x;
    for (int i = tid; i < NVOX * 64; i += stride) outp[i] = fmaf(a, outp[i], c);
}

extern "C" void kernel_launch(void* const* d_in, const int* in_sizes, int n_in,
                              void* d_out, int out_size, void* d_ws, size_t ws_size,
                              hipStream_t stream) {
    const float* vox    = (const float*)d_in[0];
    const int*   coords = (const int*)d_in[1];
    const int*   nump   = (const int*)d_in[2];
    const float* W1     = (const float*)d_in[3];
    const float* g1     = (const float*)d_in[4];
    const float* b1     = (const float*)d_in[5];
    const float* W2     = (const float*)d_in[6];
    const float* g2     = (const float*)d_in[7];
    const float* b2     = (const float*)d_in[8];
    const float* Wf     = (const float*)d_in[9];
    const float* gf     = (const float*)d_in[10];
    const float* bf     = (const float*)d_in[11];
    float* out = (float*)d_out;

    double* s1 = (double*)d_ws;   // 32 doubles
    double* s2 = s1 + 32;         // 64 doubles
    double* sf = s1 + 96;         // 128 doubles

    kz<<<1, 256, 0, stream>>>(s1);
    k1<<<512, 256, 0, stream>>>(vox, coords, W1, s1);
    k2<<<1024, 256, 0, stream>>>(vox, coords, nump, W1, g1, b1, W2, s1, s2);
    k3<<<1024, 256, 0, stream>>>(vox, coords, nump, W1, g1, b1, W2, g2, b2, Wf, s1, s2, sf, out);
    k4<<<2048, 256, 0, stream>>>(out, gf, bf, sf);
}

// Round 2
// 317.047 us; speedup vs baseline: 2.1429x; 2.1429x over previous
//
#include <hip/hip_runtime.h>

#define BB 2
#define VV 16000
#define PP 32
#define NVOX (BB*VV)      // 32000
#define NPTS (NVOX*PP)    // 1024000
#define NGRP 16000        // groups for k2/k3: 2000 blocks * 8 groups
#define NITER 2           // NVOX / NGRP

// wave-internal LDS fence: all intra-group comm is intra-wave (lockstep),
// so a lgkmcnt drain is sufficient -- no s_barrier needed.
#define FENCE() asm volatile("s_waitcnt lgkmcnt(0)" ::: "memory")

// ---------------- zero the stats accumulators in ws ----------------
__global__ void kz(double* __restrict__ s) {
    if (threadIdx.x < 224) s[threadIdx.x] = 0.0;
}

// ---------------- k1: stats of h1pre (16 ch) over all points ----------------
__global__ __launch_bounds__(256) void k1(const float* __restrict__ vox,
                                          const int* __restrict__ coords,
                                          const float* __restrict__ W1,
                                          double* __restrict__ s1) {
    float sum[16], sq[16];
#pragma unroll
    for (int o = 0; o < 16; o++) { sum[o] = 0.f; sq[o] = 0.f; }
    const int stride = gridDim.x * blockDim.x;
    for (int i = blockIdx.x * blockDim.x + threadIdx.x; i < NPTS; i += stride) {
        const int vx = i >> 5;
        const float4 q = reinterpret_cast<const float4*>(vox)[i];
        const int4 c4 = reinterpret_cast<const int4*>(coords)[vx];
        const float cx = ((float)c4.w + 0.5f) * 0.16f + 0.0f;
        const float cy = ((float)c4.z + 0.5f) * 0.16f - 39.68f;
        const float cz = ((float)c4.y + 0.5f) * 4.0f  - 3.0f;
        const float f[8] = {q.x, q.y, q.z, q.x - cx, q.y - cy, q.z - cz, q.w, q.z};
#pragma unroll
        for (int o = 0; o < 16; o++) {
            float h = 0.f;
#pragma unroll
            for (int c = 0; c < 8; c++) h = fmaf(f[c], W1[o * 8 + c], h);
            sum[o] += h;
            sq[o] = fmaf(h, h, sq[o]);
        }
    }
    __shared__ double red[4][32];
    const int lane = threadIdx.x & 63, wv = threadIdx.x >> 6;
#pragma unroll
    for (int o = 0; o < 16; o++) {
        float s = sum[o], g = sq[o];
#pragma unroll
        for (int m = 1; m < 64; m <<= 1) { s += __shfl_xor(s, m); g += __shfl_xor(g, m); }
        if (lane == 0) { red[wv][o] = (double)s; red[wv][16 + o] = (double)g; }
    }
    __syncthreads();
    if (threadIdx.x < 32) {
        double t = red[0][threadIdx.x] + red[1][threadIdx.x] + red[2][threadIdx.x] + red[3][threadIdx.x];
        atomicAdd(&s1[threadIdx.x], t);
    }
}

// ---------------- k2: stats of h2pre (32 ch) over all points ----------------
// group = 32 lanes (half-wave); layer-1 max via XOR-swizzled LDS transpose.
__global__ __launch_bounds__(256) void k2(const float* __restrict__ vox,
                                          const int* __restrict__ coords,
                                          const int* __restrict__ nump,
                                          const float* __restrict__ W1,
                                          const float* __restrict__ g1v,
                                          const float* __restrict__ b1v,
                                          const float* __restrict__ W2,
                                          const double* __restrict__ s1,
                                          double* __restrict__ s2) {
    __shared__ float tile[8][16][32];      // t1 transpose / tail-reduce scratch
    __shared__ float pm[8][32];            // layer-1 partial maxes
    __shared__ float gred[8][2][32];       // per-group channel sums / sqsums
    __shared__ float a1s[16], c1s[16];
    if (threadIdx.x < 16) {
        const int o = threadIdx.x;
        const double mean = s1[o] * (1.0 / NPTS);
        const double var  = s1[16 + o] * (1.0 / NPTS) - mean * mean;
        const float inv = rsqrtf((float)var + 1e-3f);
        const float a = g1v[o] * inv;
        a1s[o] = a;
        c1s[o] = b1v[o] - (float)mean * a;
    }
    __syncthreads();

    const int g = threadIdx.x >> 5;
    const int p = threadIdx.x & 31;
    const int ch = p & 15, hf = p >> 4;

    float sum2[32], sq2[32];
#pragma unroll
    for (int o = 0; o < 32; o++) { sum2[o] = 0.f; sq2[o] = 0.f; }

    const int gid0 = blockIdx.x * 8 + g;
#pragma unroll 1
    for (int it = 0; it < NITER; ++it) {
        const int vx = gid0 + it * NGRP;
        const int4 c4 = reinterpret_cast<const int4*>(coords)[vx];
        const int np = nump[vx];
        const float4 q = reinterpret_cast<const float4*>(vox)[(vx << 5) + p];
        const float cx = ((float)c4.w + 0.5f) * 0.16f + 0.0f;
        const float cy = ((float)c4.z + 0.5f) * 0.16f - 39.68f;
        const float cz = ((float)c4.y + 0.5f) * 4.0f  - 3.0f;
        const float f[8] = {q.x, q.y, q.z, q.x - cx, q.y - cy, q.z - cz, q.w, q.z};
        float h1r[16];
#pragma unroll
        for (int o = 0; o < 16; o++) {
            float h = 0.f;
#pragma unroll
            for (int c = 0; c < 8; c++) h = fmaf(f[c], W1[o * 8 + c], h);
            h1r[o] = fmaxf(fmaf(a1s[o], h, c1s[o]), 0.f);
            tile[g][o][p ^ o] = h1r[o];
        }
        FENCE();
        // lane p folds (channel p&15, half p>>4): 16 independent reads + maxes
        {
            float m = tile[g][ch][(hf * 16 + 0) ^ ch];
#pragma unroll
            for (int j = 1; j < 16; j++) m = fmaxf(m, tile[g][ch][(hf * 16 + j) ^ ch]);
            pm[g][p] = m;
        }
        FENCE();
        const float mk = (p < np) ? 1.f : 0.f;
        float cb[32];
#pragma unroll
        for (int c = 0; c < 16; c++) {
            cb[c] = mk * h1r[c];
            cb[16 + c] = mk * fmaxf(pm[g][c], pm[g][16 + c]);
        }
#pragma unroll
        for (int o = 0; o < 32; o++) {
            float h = 0.f;
#pragma unroll
            for (int c = 0; c < 32; c++) h = fmaf(cb[c], W2[o * 32 + c], h);
            sum2[o] += h;
            sq2[o] = fmaf(h, h, sq2[o]);
        }
    }

    // tail: transpose-reduce the per-lane accumulators (4 passes over tile)
#pragma unroll
    for (int pass = 0; pass < 4; pass++) {
        const int qi = pass >> 1, hb = pass & 1;
        FENCE();
#pragma unroll
        for (int c = 0; c < 16; c++) {
            const float v = qi ? sq2[hb * 16 + c] : sum2[hb * 16 + c];
            tile[g][c][p ^ c] = v;
        }
        FENCE();
        float s = 0.f;
#pragma unroll
        for (int j = 0; j < 16; j++) s += tile[g][ch][(hf * 16 + j) ^ ch];
        s += __shfl_xor(s, 16);
        if (p < 16) gred[g][qi][hb * 16 + p] = s;
    }
    __syncthreads();
    if (threadIdx.x < 64) {
        const int qi = threadIdx.x >> 5, c = threadIdx.x & 31;
        double t = 0.0;
#pragma unroll
        for (int gg = 0; gg < 8; gg++) t += (double)gred[gg][qi][c];
        atomicAdd(&s2[qi * 32 + c], t);
    }
}

// ---------------- k3: recompute, voxel features, final matmul, statsf ----------------
__global__ __launch_bounds__(256) void k3(const float* __restrict__ vox,
                                          const int* __restrict__ coords,
                                          const int* __restrict__ nump,
                                          const float* __restrict__ W1,
                                          const float* __restrict__ g1v,
                                          const float* __restrict__ b1v,
                                          const float* __restrict__ W2,
                                          const float* __restrict__ g2v,
                                          const float* __restrict__ b2v,
                                          const float* __restrict__ Wf,
                                          const double* __restrict__ s1,
                                          const double* __restrict__ s2,
                                          double* __restrict__ sf,
                                          float* __restrict__ outp) {
    __shared__ float wf[64 * 64];              // XOR-2 swizzled (2-way = free)
    __shared__ float tile[8][32][32];          // h1/h2 transpose, XOR swizzle
    __shared__ __align__(16) float vfb[8][64]; // pm overlay, then vf broadcast row
    __shared__ float red[4][32][4];
    __shared__ float a1s[16], c1s[16], a2s[32], c2s[32];

    for (int i = threadIdx.x; i < 64 * 64; i += 256) {
        const int o = i >> 6, c = i & 63;
        wf[o * 64 + (c ^ ((o & 15) << 1))] = Wf[i];
    }
    if (threadIdx.x < 16) {
        const int o = threadIdx.x;
        const double mean = s1[o] * (1.0 / NPTS);
        const double var  = s1[16 + o] * (1.0 / NPTS) - mean * mean;
        const float inv = rsqrtf((float)var + 1e-3f);
        const float a = g1v[o] * inv;
        a1s[o] = a;
        c1s[o] = b1v[o] - (float)mean * a;
    }
    if (threadIdx.x >= 32 && threadIdx.x < 64) {
        const int o = threadIdx.x - 32;
        const double mean = s2[o] * (1.0 / NPTS);
        const double var  = s2[32 + o] * (1.0 / NPTS) - mean * mean;
        const float inv = rsqrtf((float)var + 1e-3f);
        const float a = g2v[o] * inv;
        a2s[o] = a;
        c2s[o] = b2v[o] - (float)mean * a;
    }
    __syncthreads();

    const int g = threadIdx.x >> 5;
    const int p = threadIdx.x & 31;
    const int ch = p & 15, hf = p >> 4;
    const int sp = (p & 15) << 1;

    float ts0 = 0.f, tq0 = 0.f, ts1 = 0.f, tq1 = 0.f;
    const int gid0 = blockIdx.x * 8 + g;
#pragma unroll 1
    for (int it = 0; it < NITER; ++it) {
        const int vx = gid0 + it * NGRP;
        const int4 c4 = reinterpret_cast<const int4*>(coords)[vx];
        const int np = nump[vx];
        const float4 q = reinterpret_cast<const float4*>(vox)[(vx << 5) + p];
        const float cx = ((float)c4.w + 0.5f) * 0.16f + 0.0f;
        const float cy = ((float)c4.z + 0.5f) * 0.16f - 39.68f;
        const float cz = ((float)c4.y + 0.5f) * 4.0f  - 3.0f;
        const float f[8] = {q.x, q.y, q.z, q.x - cx, q.y - cy, q.z - cz, q.w, q.z};
        float h1r[16];
#pragma unroll
        for (int o = 0; o < 16; o++) {
            float h = 0.f;
#pragma unroll
            for (int c = 0; c < 8; c++) h = fmaf(f[c], W1[o * 8 + c], h);
            h1r[o] = fmaxf(fmaf(a1s[o], h, c1s[o]), 0.f);
            tile[g][o][p ^ o] = h1r[o];
        }
        FENCE();
        {
            float m = tile[g][ch][(hf * 16 + 0) ^ ch];
#pragma unroll
            for (int j = 1; j < 16; j++) m = fmaxf(m, tile[g][ch][(hf * 16 + j) ^ ch]);
            vfb[g][p] = m;   // pm overlay
        }
        FENCE();
        const float mk = (p < np) ? 1.f : 0.f;
        float cb[32];
#pragma unroll
        for (int c = 0; c < 16; c++) {
            cb[c] = mk * h1r[c];
            cb[16 + c] = mk * fmaxf(vfb[g][c], vfb[g][16 + c]);
        }
#pragma unroll
        for (int o = 0; o < 32; o++) {
            float h = 0.f;
#pragma unroll
            for (int c = 0; c < 32; c++) h = fmaf(cb[c], W2[o * 32 + c], h);
            const float h2 = fmaxf(fmaf(a2s[o], h, c2s[o]), 0.f);
            tile[g][o][p ^ o] = h2;
        }
        FENCE();
        // lane p folds channel p over the 32 points
        {
            float vfa = 0.f, vfm = 0.f;
#pragma unroll
            for (int j = 0; j < 32; j++) {
                const float v = tile[g][p][j ^ p];
                vfa = fmaxf(vfa, v);
                vfm = fmaxf(vfm, (j < np) ? v : 0.f);
            }
            vfb[g][p] = vfm;
            vfb[g][32 + p] = (np > 0) ? vfa : 0.f;
        }
        FENCE();
        float acc0 = 0.f, acc1 = 0.f;
#pragma unroll
        for (int c = 0; c < 64; c += 4) {
            const float4 vv = *reinterpret_cast<const float4*>(&vfb[g][c]);
            const float2 wa0 = *reinterpret_cast<const float2*>(&wf[p * 64 + ((c) ^ sp)]);
            const float2 wa1 = *reinterpret_cast<const float2*>(&wf[p * 64 + ((c + 2) ^ sp)]);
            const float2 wb0 = *reinterpret_cast<const float2*>(&wf[(p + 32) * 64 + ((c) ^ sp)]);
            const float2 wb1 = *reinterpret_cast<const float2*>(&wf[(p + 32) * 64 + ((c + 2) ^ sp)]);
            acc0 += vv.x * wa0.x + vv.y * wa0.y + vv.z * wa1.x + vv.w * wa1.y;
            acc1 += vv.x * wb0.x + vv.y * wb0.y + vv.z * wb1.x + vv.w * wb1.y;
        }
        outp[(vx << 6) + p] = acc0;
        outp[(vx << 6) + 32 + p] = acc1;
        ts0 += acc0; tq0 = fmaf(acc0, acc0, tq0);
        ts1 += acc1; tq1 = fmaf(acc1, acc1, tq1);
    }

    // statsf: fold the wave's two groups, then block-fold, then atomics
    ts0 += __shfl_xor(ts0, 32); tq0 += __shfl_xor(tq0, 32);
    ts1 += __shfl_xor(ts1, 32); tq1 += __shfl_xor(tq1, 32);
    const int wv = threadIdx.x >> 6, ln = threadIdx.x & 63;
    if (ln < 32) {
        red[wv][ln][0] = ts0; red[wv][ln][1] = tq0;
        red[wv][ln][2] = ts1; red[wv][ln][3] = tq1;
    }
    __syncthreads();
    if (threadIdx.x < 32) {
        const int pp = threadIdx.x;
        double S0 = 0, Q0 = 0, S1 = 0, Q1 = 0;
#pragma unroll
        for (int w = 0; w < 4; w++) {
            S0 += (double)red[w][pp][0]; Q0 += (double)red[w][pp][1];
            S1 += (double)red[w][pp][2]; Q1 += (double)red[w][pp][3];
        }
        atomicAdd(&sf[pp], S0);       atomicAdd(&sf[64 + pp], Q0);
        atomicAdd(&sf[32 + pp], S1);  atomicAdd(&sf[96 + pp], Q1);
    }
}

// ---------------- k4: final BN, in-place on d_out ----------------
__global__ __launch_bounds__(256) void k4(float* __restrict__ outp,
                                          const float* __restrict__ gf,
                                          const float* __restrict__ bf,
                                          const double* __restrict__ sf) {
    const int tid = blockIdx.x * blockDim.x + threadIdx.x;
    const int o = tid & 63;
    const double mean = sf[o] * (1.0 / NVOX);
    const double var  = sf[64 + o] * (1.0 / NVOX) - mean * mean;
    const float a = gf[o] * rsqrtf((float)var + 1e-5f);
    const float c = bf[o] - (float)mean * a;
    const int stride = gridDim.x * blockDim.x;
    for (int i = tid; i < NVOX * 64; i += stride) outp[i] = fmaf(a, outp[i], c);
}

extern "C" void kernel_launch(void* const* d_in, const int* in_sizes, int n_in,
                              void* d_out, int out_size, void* d_ws, size_t ws_size,
                              hipStream_t stream) {
    const float* vox    = (const float*)d_in[0];
    const int*   coords = (const int*)d_in[1];
    const int*   nump   = (const int*)d_in[2];
    const float* W1     = (const float*)d_in[3];
    const float* g1     = (const float*)d_in[4];
    const float* b1     = (const float*)d_in[5];
    const float* W2     = (const float*)d_in[6];
    const float* g2     = (const float*)d_in[7];
    const float* b2     = (const float*)d_in[8];
    const float* Wf     = (const float*)d_in[9];
    const float* gf     = (const float*)d_in[10];
    const float* bf     = (const float*)d_in[11];
    float* out = (float*)d_out;

    double* s1 = (double*)d_ws;   // 32 doubles
    double* s2 = s1 + 32;         // 64 doubles
    double* sf = s1 + 96;         // 128 doubles

    kz<<<1, 256, 0, stream>>>(s1);
    k1<<<512, 256, 0, stream>>>(vox, coords, W1, s1);
    k2<<<2000, 256, 0, stream>>>(vox, coords, nump, W1, g1, b1, W2, s1, s2);
    k3<<<2000, 256, 0, stream>>>(vox, coords, nump, W1, g1, b1, W2, g2, b2, Wf, s1, s2, sf, out);
    k4<<<2048, 256, 0, stream>>>(out, gf, bf, sf);
}